// Round 1
// baseline (11053.559 us; speedup 1.0000x reference)
//
#include <hip/hip_runtime.h>
#include <hip/hip_bf16.h>

#define N_NODES 10000
#define N_EDGES 160000
#define N_GRAPHS 64
#define EMB 128
#define M_DIM 32
#define NK 5
#define EPS 1e-5f

__device__ __forceinline__ float silu(float x) { return x / (1.0f + __expf(-x)); }
__device__ __forceinline__ float4 f4fma(float s, float4 w, float4 a) {
    a.x = fmaf(s, w.x, a.x); a.y = fmaf(s, w.y, a.y);
    a.z = fmaf(s, w.z, a.z); a.w = fmaf(s, w.w, a.w);
    return a;
}
__device__ __forceinline__ float wave_sum64(float v) {
    #pragma unroll
    for (int off = 32; off > 0; off >>= 1) v += __shfl_xor(v, off, 64);
    return v;
}

// ---------------- embedding ----------------
__global__ __launch_bounds__(128) void k_embed(const int* __restrict__ atomids,
                                               const float* __restrict__ emb_w,
                                               float* __restrict__ feats_all) {
    int n = blockIdx.x, tid = threadIdx.x;
    feats_all[(size_t)n * 768 + tid] = emb_w[(size_t)atomids[n] * 128 + tid];
}

// ---------------- fourier table (coords constant across layers) ----------------
__global__ __launch_bounds__(64) void k_fe(const float* __restrict__ coords,
                                           const int* __restrict__ eidx,
                                           float* __restrict__ fe) {
    int e = blockIdx.x * 64 + threadIdx.x;
    if (e >= N_EDGES) return;
    int s = eidx[e], d = eidx[N_EDGES + e];
    float dx = coords[s * 3 + 0] - coords[d * 3 + 0];
    float dy = coords[s * 3 + 1] - coords[d * 3 + 1];
    float dz = coords[s * 3 + 2] - coords[d * 3 + 2];
    float d2 = dx * dx + dy * dy + dz * dz;
    float* o = fe + (size_t)e * 65;
    float sc = 1.0f;
    #pragma unroll
    for (int i = 0; i < 32; ++i) {
        float x = d2 * sc;
        o[i] = sinf(x);
        o[32 + i] = cosf(x);
        sc *= 0.5f;
    }
    o[64] = d2;
}

// ---------------- generic fp32 GEMM: C[M][N] = act(actA(A)[M][K] @ B[K][N] + bias) ----------------
// 64x128 tile, 256 threads, each thread 4 rows x 8 cols. K must be a multiple of 32.
__global__ __launch_bounds__(256) void k_fc(const float* __restrict__ A, int lda,
                                            const float* __restrict__ B, int ldb,
                                            const float* __restrict__ bias,
                                            float* __restrict__ C, int ldc,
                                            int M, int N, int K, int siluA, int siluOut) {
    __shared__ float As[64 * 33];
    __shared__ float Bs[32 * 132];
    int tid = threadIdx.x;
    int m0 = blockIdx.x * 64, n0 = blockIdx.y * 128;
    int tn = tid >> 4, tc = tid & 15;  // rows 4*tn.., cols 8*tc..

    float4 acc[4][2];
    #pragma unroll
    for (int i = 0; i < 4; ++i) { acc[i][0] = make_float4(0,0,0,0); acc[i][1] = make_float4(0,0,0,0); }

    for (int kc = 0; kc < K; kc += 32) {
        for (int idx = tid; idx < 2048; idx += 256) {
            int r = idx >> 5, c = idx & 31;
            int m = m0 + r;
            float a = (m < M) ? A[(size_t)m * lda + kc + c] : 0.f;
            if (siluA) a = silu(a);
            As[r * 33 + c] = a;
        }
        for (int idx = tid; idx < 4096; idx += 256) {
            int r = idx >> 7, c = idx & 127;
            int n = n0 + c;
            Bs[r * 132 + c] = (n < N) ? B[(size_t)(kc + r) * ldb + n] : 0.f;
        }
        __syncthreads();
        #pragma unroll 4
        for (int kk = 0; kk < 32; ++kk) {
            float a0 = As[(4 * tn + 0) * 33 + kk];
            float a1 = As[(4 * tn + 1) * 33 + kk];
            float a2 = As[(4 * tn + 2) * 33 + kk];
            float a3 = As[(4 * tn + 3) * 33 + kk];
            float4 b0 = *(const float4*)&Bs[kk * 132 + 8 * tc];
            float4 b1 = *(const float4*)&Bs[kk * 132 + 8 * tc + 4];
            acc[0][0] = f4fma(a0, b0, acc[0][0]); acc[0][1] = f4fma(a0, b1, acc[0][1]);
            acc[1][0] = f4fma(a1, b0, acc[1][0]); acc[1][1] = f4fma(a1, b1, acc[1][1]);
            acc[2][0] = f4fma(a2, b0, acc[2][0]); acc[2][1] = f4fma(a2, b1, acc[2][1]);
            acc[3][0] = f4fma(a3, b0, acc[3][0]); acc[3][1] = f4fma(a3, b1, acc[3][1]);
        }
        __syncthreads();
    }
    #pragma unroll
    for (int i = 0; i < 4; ++i) {
        int m = m0 + 4 * tn + i;
        if (m >= M) continue;
        float vals[8] = {acc[i][0].x, acc[i][0].y, acc[i][0].z, acc[i][0].w,
                         acc[i][1].x, acc[i][1].y, acc[i][1].z, acc[i][1].w};
        #pragma unroll
        for (int c = 0; c < 8; ++c) {
            int n = n0 + 8 * tc + c;
            if (n >= N) continue;
            float v = vals[c] + (bias ? bias[n] : 0.f);
            if (siluOut) v = silu(v);
            C[(size_t)m * ldc + n] = v;
        }
    }
}

// ---------------- fused edge kernel ----------------
// 32 edges per block. Phase 1: z[32][642] = fe@W1c + Pa[dst] + Pb[src] + b1, silu -> regs.
// Phase 2: m2 = silu(z)@W2 + b2 (via LDS transpose), silu, LN, atomic segment add.
__global__ __launch_bounds__(256) void k_edge(const float* __restrict__ fe,
                                              const float* __restrict__ Pab,
                                              const int* __restrict__ eidx,
                                              const float* __restrict__ W1c,   // [65][642]
                                              const float* __restrict__ b1,    // [642]
                                              const float* __restrict__ W2,    // [642][32]
                                              const float* __restrict__ b2,    // [32]
                                              const float* __restrict__ eng,
                                              const float* __restrict__ enb,
                                              float* __restrict__ S,
                                              float* __restrict__ cnt) {
    __shared__ float U[9808];
    __shared__ int di[32], si[32];
    float* feT2 = U;          // [65][32]  phase 1
    float* WL   = U + 2080;   // [12][644] phase 1
    float* T2   = U;          // [128][33] phase 2
    float* W2c  = U + 4224;   // [128][32] phase 2
    float* m2L  = U + 8320;   // [32][33]
    float* zrL  = U + 9376;   // [32][2]
    float* stat = U + 9440;   // [32][2]

    const int tid = threadIdx.x;
    const int e0 = blockIdx.x * 32;
    const int ct = tid & 31, eg = tid >> 5;

    if (tid < 32) {
        si[tid] = eidx[e0 + tid];
        di[tid] = eidx[N_EDGES + e0 + tid];
    }
    for (int idx = tid; idx < 2080; idx += 256) {
        int e = idx / 65, kk = idx - e * 65;
        feT2[kk * 32 + e] = fe[(size_t)e0 * 65 + idx];
    }
    __syncthreads();

    float4 acc[4][5];
    #pragma unroll
    for (int e = 0; e < 4; ++e)
        #pragma unroll
        for (int q = 0; q < 5; ++q) acc[e][q] = make_float4(0,0,0,0);
    float racc[4][2] = {};

    int kbase = 0;
    for (int ch = 0; ch < 6; ++ch) {
        const int KT = (ch == 5) ? 5 : 12;
        for (int r = 0; r < KT; ++r)
            for (int j = tid; j < 642; j += 256)
                WL[r * 644 + j] = W1c[(size_t)(kbase + r) * 642 + j];
        __syncthreads();
        for (int kk = 0; kk < KT; ++kk) {
            const float4 ff = *(const float4*)&feT2[(kbase + kk) * 32 + 4 * eg];
            #pragma unroll
            for (int q = 0; q < 5; ++q) {
                const float4 w = *(const float4*)&WL[kk * 644 + 4 * ct + 128 * q];
                acc[0][q] = f4fma(ff.x, w, acc[0][q]);
                acc[1][q] = f4fma(ff.y, w, acc[1][q]);
                acc[2][q] = f4fma(ff.z, w, acc[2][q]);
                acc[3][q] = f4fma(ff.w, w, acc[3][q]);
            }
        }
        if (ct == 0) {
            for (int kk = 0; kk < KT; ++kk) {
                float w0 = WL[kk * 644 + 640], w1 = WL[kk * 644 + 641];
                #pragma unroll
                for (int e = 0; e < 4; ++e) {
                    float f = feT2[(kbase + kk) * 32 + 4 * eg + e];
                    racc[e][0] = fmaf(f, w0, racc[e][0]);
                    racc[e][1] = fmaf(f, w1, racc[e][1]);
                }
            }
        }
        __syncthreads();
        kbase += KT;
    }

    // epilogue phase 1: bias + gathered node projections, silu
    float4 bq[5];
    #pragma unroll
    for (int q = 0; q < 5; ++q) {
        int j = 4 * ct + 128 * q;
        bq[q] = make_float4(b1[j], b1[j + 1], b1[j + 2], b1[j + 3]);  // scalar: 8B-aligned base
    }
    #pragma unroll
    for (int e = 0; e < 4; ++e) {
        const float* Par = Pab + (size_t)di[4 * eg + e] * 1288;
        const float* Pbr = Pab + (size_t)si[4 * eg + e] * 1288 + 644;
        #pragma unroll
        for (int q = 0; q < 5; ++q) {
            int j = 4 * ct + 128 * q;
            float4 pa = *(const float4*)(Par + j);
            float4 pb = *(const float4*)(Pbr + j);
            float4 z = acc[e][q];
            z.x = silu(z.x + pa.x + pb.x + bq[q].x);
            z.y = silu(z.y + pa.y + pb.y + bq[q].y);
            z.z = silu(z.z + pa.z + pb.z + bq[q].z);
            z.w = silu(z.w + pa.w + pb.w + bq[q].w);
            acc[e][q] = z;
        }
    }
    if (ct == 0) {
        float b640 = b1[640], b641 = b1[641];
        #pragma unroll
        for (int e = 0; e < 4; ++e) {
            const float* Par = Pab + (size_t)di[4 * eg + e] * 1288;
            const float* Pbr = Pab + (size_t)si[4 * eg + e] * 1288 + 644;
            float z0 = racc[e][0] + b640 + Par[640] + Pbr[640];
            float z1 = racc[e][1] + b641 + Par[641] + Pbr[641];
            zrL[(4 * eg + e) * 2 + 0] = silu(z0);
            zrL[(4 * eg + e) * 2 + 1] = silu(z1);
        }
    }

    // phase 2: m2[e][c] = sum_j silu(z)[e][j] * W2[j][c]
    const int e2 = tid & 31, cg = tid >> 5;
    float4 a2a = make_float4(0,0,0,0), a2b = make_float4(0,0,0,0);
    for (int q = 0; q < 5; ++q) {
        {
            const float4* srcp = (const float4*)(W2 + q * 4096);
            float4* dstp = (float4*)W2c;
            for (int i = tid; i < 1024; i += 256) dstp[i] = srcp[i];
        }
        #pragma unroll
        for (int ee = 0; ee < 4; ++ee) {
            float4 v = acc[ee][q];
            int eb = 4 * eg + ee;
            T2[(4 * ct + 0) * 33 + eb] = v.x;
            T2[(4 * ct + 1) * 33 + eb] = v.y;
            T2[(4 * ct + 2) * 33 + eb] = v.z;
            T2[(4 * ct + 3) * 33 + eb] = v.w;
        }
        __syncthreads();
        #pragma unroll 2
        for (int jj = 0; jj < 128; jj += 2) {
            float t0 = T2[jj * 33 + e2];
            float t1 = T2[(jj + 1) * 33 + e2];
            float4 w0 = *(const float4*)&W2c[jj * 32 + 4 * cg];
            float4 w1 = *(const float4*)&W2c[(jj + 1) * 32 + 4 * cg];
            a2a = f4fma(t0, w0, a2a);
            a2b = f4fma(t1, w1, a2b);
        }
        __syncthreads();
    }
    {
        float t0 = zrL[e2 * 2 + 0], t1 = zrL[e2 * 2 + 1];
        float4 w0 = *(const float4*)(W2 + 640 * 32 + 4 * cg);
        float4 w1 = *(const float4*)(W2 + 641 * 32 + 4 * cg);
        a2a = f4fma(t0, w0, a2a);
        a2b = f4fma(t1, w1, a2b);
        float4 bb = *(const float4*)(b2 + 4 * cg);
        float4 m2;
        m2.x = silu(a2a.x + a2b.x + bb.x);
        m2.y = silu(a2a.y + a2b.y + bb.y);
        m2.z = silu(a2a.z + a2b.z + bb.z);
        m2.w = silu(a2a.w + a2b.w + bb.w);
        m2L[e2 * 33 + 4 * cg + 0] = m2.x;
        m2L[e2 * 33 + 4 * cg + 1] = m2.y;
        m2L[e2 * 33 + 4 * cg + 2] = m2.z;
        m2L[e2 * 33 + 4 * cg + 3] = m2.w;
    }
    __syncthreads();
    if (tid < 32) {
        float s = 0.f, ss = 0.f;
        #pragma unroll
        for (int c = 0; c < 32; ++c) {
            float v = m2L[tid * 33 + c];
            s += v; ss += v * v;
        }
        float mean = s * (1.0f / 32.0f);
        float var = ss * (1.0f / 32.0f) - mean * mean;
        stat[tid * 2 + 0] = mean;
        stat[tid * 2 + 1] = 1.0f / sqrtf(var + EPS);
    }
    __syncthreads();
    {
        float mean = stat[e2 * 2], rstd = stat[e2 * 2 + 1];
        int d = di[e2];
        #pragma unroll
        for (int c = 0; c < 4; ++c) {
            int cc = 4 * cg + c;
            float v = (m2L[e2 * 33 + cc] - mean) * rstd * eng[cc] + enb[cc];
            atomicAdd(&S[(size_t)d * 32 + cc], v);
        }
    }
    if (tid < 32) atomicAdd(&cnt[di[tid]], 1.0f);
}

// ---------------- node prep: H0 = [LN(feats) | LN(S/cnt)] ----------------
__global__ __launch_bounds__(128) void k_prep(const float* __restrict__ featsk,
                                              const float* __restrict__ S,
                                              const float* __restrict__ cnt,
                                              const float* __restrict__ nn1g,
                                              const float* __restrict__ nn1b,
                                              const float* __restrict__ eng,
                                              const float* __restrict__ enb,
                                              float* __restrict__ H0) {
    int n = blockIdx.x, tid = threadIdx.x;
    __shared__ float red[4];
    float x = featsk[(size_t)n * 768 + tid];
    float s = wave_sum64(x), ss = wave_sum64(x * x);
    if ((tid & 63) == 0) { red[(tid >> 6) * 2] = s; red[(tid >> 6) * 2 + 1] = ss; }
    __syncthreads();
    float S1 = red[0] + red[2], S2 = red[1] + red[3];
    float mean = S1 * (1.0f / 128.0f);
    float var = S2 * (1.0f / 128.0f) - mean * mean;
    float rstd = 1.0f / sqrtf(var + EPS);
    H0[(size_t)n * 160 + tid] = (x - mean) * rstd * nn1g[tid] + nn1b[tid];
    if (tid < 32) {
        float inv = 1.0f / fmaxf(cnt[n], 1.0f);
        float v = S[(size_t)n * 32 + tid] * inv;
        float s2 = v, q2 = v * v;
        #pragma unroll
        for (int off = 16; off > 0; off >>= 1) {
            s2 += __shfl_xor(s2, off, 64);
            q2 += __shfl_xor(q2, off, 64);
        }
        float m2 = s2 * (1.0f / 32.0f);
        float va = q2 * (1.0f / 32.0f) - m2 * m2;
        float rs = 1.0f / sqrtf(va + EPS);
        H0[(size_t)n * 160 + 128 + tid] = (v - m2) * rs * eng[tid] + enb[tid];
    }
}

// ---------------- LN + residual ----------------
__global__ __launch_bounds__(128) void k_ln_res(const float* __restrict__ H2,
                                                float* __restrict__ feats_all, int k,
                                                const float* __restrict__ g,
                                                const float* __restrict__ b) {
    int n = blockIdx.x, tid = threadIdx.x;
    __shared__ float red[4];
    float x = H2[(size_t)n * 128 + tid];
    float s = wave_sum64(x), ss = wave_sum64(x * x);
    if ((tid & 63) == 0) { red[(tid >> 6) * 2] = s; red[(tid >> 6) * 2 + 1] = ss; }
    __syncthreads();
    float S1 = red[0] + red[2], S2 = red[1] + red[3];
    float mean = S1 * (1.0f / 128.0f);
    float var = S2 * (1.0f / 128.0f) - mean * mean;
    float rstd = 1.0f / sqrtf(var + EPS);
    float v = (x - mean) * rstd * g[tid] + b[tid];
    float f = feats_all[(size_t)n * 768 + k * 128 + tid];
    feats_all[(size_t)n * 768 + (k + 1) * 128 + tid] = f + v;
}

// ---------------- graph pooling (batch is sorted -> run-length local accum) ----------------
__global__ __launch_bounds__(256) void k_pool(const float* __restrict__ F,
                                              const int* __restrict__ batch,
                                              float* __restrict__ G,
                                              float* __restrict__ cntg) {
    __shared__ int bL[32];
    int b0 = blockIdx.x * 32;
    int tid = threadIdx.x;
    int nmax = min(32, N_NODES - b0);
    if (nmax <= 0) return;
    if (tid < nmax) bL[tid] = batch[b0 + tid];
    __syncthreads();
    float accv = 0.f;
    int cur = -1;
    for (int i = 0; i < nmax; ++i) {
        int g = bL[i];
        if (g != cur) {
            if (cur >= 0) atomicAdd(&G[(size_t)cur * 256 + tid], accv);
            cur = g; accv = 0.f;
        }
        accv += F[(size_t)(b0 + i) * 256 + tid];
    }
    if (cur >= 0) atomicAdd(&G[(size_t)cur * 256 + tid], accv);
    if (tid == 0)
        for (int i = 0; i < nmax; ++i) atomicAdd(&cntg[bL[i]], 1.0f);
}

// ---------------- per-graph MLP head ----------------
__global__ __launch_bounds__(256) void k_graph(const float* __restrict__ G,
                                               const float* __restrict__ cntg,
                                               const float* __restrict__ g1W,
                                               const float* __restrict__ g1b,
                                               const float* __restrict__ g2W,
                                               const float* __restrict__ g2b,
                                               const float* __restrict__ g3W,
                                               const float* __restrict__ g3b,
                                               float* __restrict__ out) {
    __shared__ float X[256], Y[256], red[4];
    int g = blockIdx.x, tid = threadIdx.x;
    float inv = 1.0f / fmaxf(cntg[g], 1.0f);
    X[tid] = G[(size_t)g * 256 + tid] * inv;
    __syncthreads();
    float a = g1b[tid];
    for (int j = 0; j < 256; ++j) a = fmaf(X[j], g1W[(size_t)j * 256 + tid], a);
    Y[tid] = silu(a);
    __syncthreads();
    a = g2b[tid];
    for (int j = 0; j < 256; ++j) a = fmaf(Y[j], g2W[(size_t)j * 256 + tid], a);
    float z = silu(a);
    float p = z * g3W[tid];
    p = wave_sum64(p);
    if ((tid & 63) == 0) red[tid >> 6] = p;
    __syncthreads();
    if (tid == 0) out[g] = red[0] + red[1] + red[2] + red[3] + g3b[0];
}

extern "C" void kernel_launch(void* const* d_in, const int* in_sizes, int n_in,
                              void* d_out, int out_size, void* d_ws, size_t ws_size,
                              hipStream_t stream) {
    const int*   atomids = (const int*)d_in[0];
    const float* coords  = (const float*)d_in[1];
    const int*   eidx    = (const int*)d_in[2];
    const int*   batch   = (const int*)d_in[3];
    const float* emb_w   = (const float*)d_in[4];
    const float* eW1     = (const float*)d_in[5];
    const float* eb1     = (const float*)d_in[6];
    const float* eW2     = (const float*)d_in[7];
    const float* eb2     = (const float*)d_in[8];
    const float* en_g    = (const float*)d_in[9];
    const float* en_b    = (const float*)d_in[10];
    const float* nn1_g   = (const float*)d_in[11];
    const float* nn1_b   = (const float*)d_in[12];
    const float* nW1     = (const float*)d_in[13];
    const float* nb1     = (const float*)d_in[14];
    const float* nW2     = (const float*)d_in[15];
    const float* nb2     = (const float*)d_in[16];
    const float* nn2_g   = (const float*)d_in[17];
    const float* nn2_b   = (const float*)d_in[18];
    const float* f1W     = (const float*)d_in[19];
    const float* f1b     = (const float*)d_in[20];
    const float* f2W     = (const float*)d_in[21];
    const float* f2b     = (const float*)d_in[22];
    const float* f3W     = (const float*)d_in[23];
    const float* f3b     = (const float*)d_in[24];
    const float* g1W     = (const float*)d_in[25];
    const float* g1b     = (const float*)d_in[26];
    const float* g2W     = (const float*)d_in[27];
    const float* g2b     = (const float*)d_in[28];
    const float* g3W     = (const float*)d_in[29];
    const float* g3b     = (const float*)d_in[30];
    float* out = (float*)d_out;

    float* ws = (float*)d_ws;
    float* feats_all = ws;                     // [10000][768]
    float* feP  = feats_all + 7680000;         // [160000][65]
    float* Pab  = feP + 10400000;              // [10000][2][644]
    float* S    = Pab + 12880000;              // [10000][32]
    float* cnt  = S + 320000;                  // [10000]
    float* H0   = cnt + 10000;                 // [10000][160]
    float* H1   = H0 + 1600000;                // [10000][256] (also F1)
    float* H2   = H1 + 2560000;                // [10000][128]
    float* F2   = H2 + 1280000;                // [10000][256]
    float* G    = F2 + 2560000;                // [64][256]
    float* cntg = G + 16384;                   // [64]
    float* F3   = Pab;                         // reuse Pab region for F3 [10000][256]

    k_embed<<<N_NODES, 128, 0, stream>>>(atomids, emb_w, feats_all);
    k_fe<<<N_EDGES / 64, 64, 0, stream>>>(coords, eidx, feP);

    for (int k = 0; k < NK; ++k) {
        const float* eW1k = eW1 + (size_t)k * 321 * 642;
        const float* eb1k = eb1 + (size_t)k * 642;
        const float* eW2k = eW2 + (size_t)k * 642 * 32;
        const float* eb2k = eb2 + (size_t)k * 32;
        const float* engk = en_g + (size_t)k * 32;
        const float* enbk = en_b + (size_t)k * 32;
        const float* nn1gk = nn1_g + (size_t)k * 128;
        const float* nn1bk = nn1_b + (size_t)k * 128;
        const float* nW1k = nW1 + (size_t)k * 160 * 256;
        const float* nb1k = nb1 + (size_t)k * 256;
        const float* nW2k = nW2 + (size_t)k * 256 * 128;
        const float* nb2k = nb2 + (size_t)k * 128;
        const float* nn2gk = nn2_g + (size_t)k * 128;
        const float* nn2bk = nn2_b + (size_t)k * 128;

        // node projections Pa = feats @ W1[0:128], Pb = feats @ W1[128:256]
        k_fc<<<dim3(157, 6), 256, 0, stream>>>(feats_all + k * 128, 768, eW1k, 642,
                                               nullptr, Pab, 1288, N_NODES, 642, 128, 0, 0);
        k_fc<<<dim3(157, 6), 256, 0, stream>>>(feats_all + k * 128, 768, eW1k + 128 * 642, 642,
                                               nullptr, Pab + 644, 1288, N_NODES, 642, 128, 0, 0);
        hipMemsetAsync(S, 0, (size_t)(320000 + 10000) * sizeof(float), stream);
        k_edge<<<N_EDGES / 32, 256, 0, stream>>>(feP, Pab, eidx, eW1k + 256 * 642, eb1k,
                                                 eW2k, eb2k, engk, enbk, S, cnt);
        k_prep<<<N_NODES, 128, 0, stream>>>(feats_all + k * 128, S, cnt,
                                            nn1gk, nn1bk, engk, enbk, H0);
        k_fc<<<dim3(157, 2), 256, 0, stream>>>(H0, 160, nW1k, 256, nb1k, H1, 256,
                                               N_NODES, 256, 160, 0, 1);
        k_fc<<<dim3(157, 1), 256, 0, stream>>>(H1, 256, nW2k, 128, nb2k, H2, 128,
                                               N_NODES, 128, 256, 0, 0);
        k_ln_res<<<N_NODES, 128, 0, stream>>>(H2, feats_all, k, nn2gk, nn2bk);
    }

    // final node MLP
    k_fc<<<dim3(157, 2), 256, 0, stream>>>(feats_all, 768, f1W, 256, f1b, H1, 256,
                                           N_NODES, 256, 768, 1, 1);
    k_fc<<<dim3(157, 2), 256, 0, stream>>>(H1, 256, f2W, 256, f2b, F2, 256,
                                           N_NODES, 256, 256, 0, 1);
    k_fc<<<dim3(157, 2), 256, 0, stream>>>(F2, 256, f3W, 256, f3b, F3, 256,
                                           N_NODES, 256, 256, 0, 1);

    hipMemsetAsync(G, 0, (size_t)(16384 + 64) * sizeof(float), stream);
    k_pool<<<313, 256, 0, stream>>>(F3, batch, G, cntg);
    k_graph<<<N_GRAPHS, 256, 0, stream>>>(G, cntg, g1W, g1b, g2W, g2b, g3W, g3b, out);
}

// Round 2
// 7515.026 us; speedup vs baseline: 1.4709x; 1.4709x over previous
//
#include <hip/hip_runtime.h>
#include <hip/hip_bf16.h>

#define N_NODES 10000
#define N_EDGES 160000
#define N_GRAPHS 64
#define NK 5
#define EPS 1e-5f

__device__ __forceinline__ float silu(float x) { return x / (1.0f + __expf(-x)); }
__device__ __forceinline__ float4 f4fma(float s, float4 w, float4 a) {
    a.x = fmaf(s, w.x, a.x); a.y = fmaf(s, w.y, a.y);
    a.z = fmaf(s, w.z, a.z); a.w = fmaf(s, w.w, a.w);
    return a;
}
__device__ __forceinline__ float wave_sum64(float v) {
    #pragma unroll
    for (int off = 32; off > 0; off >>= 1) v += __shfl_xor(v, off, 64);
    return v;
}

// ---------------- embedding ----------------
__global__ __launch_bounds__(128) void k_embed(const int* __restrict__ atomids,
                                               const float* __restrict__ emb_w,
                                               float* __restrict__ feats_all) {
    int n = blockIdx.x, tid = threadIdx.x;
    feats_all[(size_t)n * 768 + tid] = emb_w[(size_t)atomids[n] * 128 + tid];
}

// ---------------- fourier table (coords constant across layers) ----------------
__global__ __launch_bounds__(64) void k_fe(const float* __restrict__ coords,
                                           const int* __restrict__ eidx,
                                           float* __restrict__ fe) {
    int e = blockIdx.x * 64 + threadIdx.x;
    if (e >= N_EDGES) return;
    int s = eidx[e], d = eidx[N_EDGES + e];
    float dx = coords[s * 3 + 0] - coords[d * 3 + 0];
    float dy = coords[s * 3 + 1] - coords[d * 3 + 1];
    float dz = coords[s * 3 + 2] - coords[d * 3 + 2];
    float d2 = dx * dx + dy * dy + dz * dz;
    float* o = fe + (size_t)e * 65;
    float sc = 1.0f;
    #pragma unroll
    for (int i = 0; i < 32; ++i) {
        float x = d2 * sc;
        o[i] = sinf(x);
        o[32 + i] = cosf(x);
        sc *= 0.5f;
    }
    o[64] = d2;
}

// ---------------- fp32 GEMM: C[M][N] = act(actA(A)[M][K] @ B[K][N] + bias) ----------------
// 128x128 tile, 256 threads, 8x8 micro-tile, transposed-A LDS staging.
__global__ __launch_bounds__(256) void k_gemm(const float* __restrict__ A, int lda,
                                              const float* __restrict__ B, int ldb,
                                              const float* __restrict__ bias,
                                              float* __restrict__ C, int ldc,
                                              int M, int N, int K, int siluA, int siluOut) {
    __shared__ float As[32 * 132];   // As[k][m], pad 132 keeps write conflicts <=4-way
    __shared__ float Bs[32 * 132];   // Bs[k][n]
    const int tid = threadIdx.x;
    const int m0 = blockIdx.x * 128, n0 = blockIdx.y * 128;
    const int tm = tid >> 4, tn = tid & 15;   // rows 8*tm.., cols 8*tn..

    float4 acc[8][2];
    #pragma unroll
    for (int r = 0; r < 8; ++r) { acc[r][0] = make_float4(0,0,0,0); acc[r][1] = make_float4(0,0,0,0); }

    for (int kc = 0; kc < K; kc += 32) {
        const int KT = min(32, K - kc);
        #pragma unroll
        for (int i = 0; i < 16; ++i) {           // stage A transposed: 128m x 32k
            int idx = tid + i * 256;
            int m = idx >> 5, c = idx & 31;
            int gm = m0 + m;
            float a = 0.f;
            if (c < KT && gm < M) a = A[(size_t)gm * lda + kc + c];
            if (siluA) a = silu(a);
            As[c * 132 + m] = a;
        }
        #pragma unroll
        for (int i = 0; i < 16; ++i) {           // stage B: 32k x 128n
            int idx = tid + i * 256;
            int r = idx >> 7, c = idx & 127;
            int gn = n0 + c;
            float b = 0.f;
            if (r < KT && gn < N) b = B[(size_t)(kc + r) * ldb + gn];
            Bs[r * 132 + c] = b;
        }
        __syncthreads();
        #pragma unroll 4
        for (int kk = 0; kk < KT; ++kk) {
            float4 a0 = *(const float4*)&As[kk * 132 + 8 * tm];
            float4 a1 = *(const float4*)&As[kk * 132 + 8 * tm + 4];
            float4 b0 = *(const float4*)&Bs[kk * 132 + 8 * tn];
            float4 b1 = *(const float4*)&Bs[kk * 132 + 8 * tn + 4];
            acc[0][0] = f4fma(a0.x, b0, acc[0][0]); acc[0][1] = f4fma(a0.x, b1, acc[0][1]);
            acc[1][0] = f4fma(a0.y, b0, acc[1][0]); acc[1][1] = f4fma(a0.y, b1, acc[1][1]);
            acc[2][0] = f4fma(a0.z, b0, acc[2][0]); acc[2][1] = f4fma(a0.z, b1, acc[2][1]);
            acc[3][0] = f4fma(a0.w, b0, acc[3][0]); acc[3][1] = f4fma(a0.w, b1, acc[3][1]);
            acc[4][0] = f4fma(a1.x, b0, acc[4][0]); acc[4][1] = f4fma(a1.x, b1, acc[4][1]);
            acc[5][0] = f4fma(a1.y, b0, acc[5][0]); acc[5][1] = f4fma(a1.y, b1, acc[5][1]);
            acc[6][0] = f4fma(a1.z, b0, acc[6][0]); acc[6][1] = f4fma(a1.z, b1, acc[6][1]);
            acc[7][0] = f4fma(a1.w, b0, acc[7][0]); acc[7][1] = f4fma(a1.w, b1, acc[7][1]);
        }
        __syncthreads();
    }

    const bool fullN = (n0 + 128 <= N);
    const int gn = n0 + 8 * tn;
    #pragma unroll
    for (int r = 0; r < 8; ++r) {
        int gm = m0 + 8 * tm + r;
        if (gm >= M) continue;
        float4 v0 = acc[r][0], v1 = acc[r][1];
        if (fullN) {
            if (bias) {
                v0.x += bias[gn+0]; v0.y += bias[gn+1]; v0.z += bias[gn+2]; v0.w += bias[gn+3];
                v1.x += bias[gn+4]; v1.y += bias[gn+5]; v1.z += bias[gn+6]; v1.w += bias[gn+7];
            }
            if (siluOut) {
                v0.x = silu(v0.x); v0.y = silu(v0.y); v0.z = silu(v0.z); v0.w = silu(v0.w);
                v1.x = silu(v1.x); v1.y = silu(v1.y); v1.z = silu(v1.z); v1.w = silu(v1.w);
            }
            *(float4*)&C[(size_t)gm * ldc + gn] = v0;
            *(float4*)&C[(size_t)gm * ldc + gn + 4] = v1;
        } else {
            float vv[8] = {v0.x, v0.y, v0.z, v0.w, v1.x, v1.y, v1.z, v1.w};
            #pragma unroll
            for (int j = 0; j < 8; ++j) {
                int c = gn + j;
                if (c >= N) continue;
                float v = vv[j] + (bias ? bias[c] : 0.f);
                if (siluOut) v = silu(v);
                C[(size_t)gm * ldc + c] = v;
            }
        }
    }
}

// ---------------- lean fused edge kernel ----------------
// 128 edges/block. Per 32-col chunk: z = silu(Q + Pa[dst] + Pb[src]) -> transposed LDS tile,
// accumulate m2 += z @ W2chunk. Epilogue: +b2, silu, LN(en_g,en_b), atomic segment-add.
#define EPB 128
__global__ __launch_bounds__(256) void k_edge(const float* __restrict__ Q, int ldq,
                                              const float* __restrict__ Pab,
                                              const int* __restrict__ eidx, int e0glob,
                                              const float* __restrict__ W2,   // [642][32]
                                              const float* __restrict__ b2,
                                              const float* __restrict__ eng,
                                              const float* __restrict__ enb,
                                              float* __restrict__ S,
                                              float* __restrict__ cnt) {
    __shared__ float Zs[32 * 132];   // Zs[j][e]; union with m2s[128][33] (both 4224 floats)
    __shared__ float W2s[32 * 36];
    __shared__ int dsi[EPB], ssi[EPB];
    __shared__ float cpar[96];       // b2 | eng | enb

    const int tid = threadIdx.x;
    const int eb = blockIdx.x * EPB;

    if (tid < EPB) {
        int ge = e0glob + eb + tid;
        ssi[tid] = eidx[ge];
        dsi[tid] = eidx[N_EDGES + ge];
    } else if (tid < 160) cpar[tid - 128] = b2[tid - 128];
    else if (tid < 192)   cpar[tid - 128] = eng[tid - 160];
    else if (tid < 224)   cpar[tid - 128] = enb[tid - 192];

    const int tj = tid & 7, trow = tid >> 3;   // staging roles
    const int cq = tid & 7, eg = tid >> 3;     // gemm: edges 4*eg.., cols 4*cq..
    float4 acc[4];
    #pragma unroll
    for (int i = 0; i < 4; ++i) acc[i] = make_float4(0,0,0,0);
    __syncthreads();

    for (int kc = 0; kc < 642; kc += 32) {
        const int KT = min(32, 642 - kc);
        if (tid < KT * 8) {                    // stage W2 chunk [KT][32]
            int r = tid >> 3, q = tid & 7;
            *(float4*)&W2s[r * 36 + 4 * q] = *(const float4*)&W2[(size_t)(kc + r) * 32 + 4 * q];
        }
        if (4 * tj < KT) {                     // z chunk: 128 e x KT j, transposed store
            #pragma unroll
            for (int p = 0; p < 4; ++p) {
                int er = p * 32 + trow;
                float4 q4 = *(const float4*)(Q   + (size_t)(eb + er) * ldq + kc + 4 * tj);
                float4 a4 = *(const float4*)(Pab + (size_t)dsi[er] * 1288 + kc + 4 * tj);
                float4 b4 = *(const float4*)(Pab + (size_t)ssi[er] * 1288 + 644 + kc + 4 * tj);
                Zs[(4 * tj + 0) * 132 + er] = silu(q4.x + a4.x + b4.x);
                Zs[(4 * tj + 1) * 132 + er] = silu(q4.y + a4.y + b4.y);
                Zs[(4 * tj + 2) * 132 + er] = silu(q4.z + a4.z + b4.z);
                Zs[(4 * tj + 3) * 132 + er] = silu(q4.w + a4.w + b4.w);
            }
        }
        __syncthreads();
        #pragma unroll 4
        for (int kk = 0; kk < KT; ++kk) {
            float4 z4 = *(const float4*)&Zs[kk * 132 + 4 * eg];
            float4 w4 = *(const float4*)&W2s[kk * 36 + 4 * cq];
            acc[0] = f4fma(z4.x, w4, acc[0]);
            acc[1] = f4fma(z4.y, w4, acc[1]);
            acc[2] = f4fma(z4.z, w4, acc[2]);
            acc[3] = f4fma(z4.w, w4, acc[3]);
        }
        __syncthreads();
    }

    // m2 = silu(acc + b2) -> m2s (reuse Zs)
    float* m2s = Zs;
    {
        float4 bb = *(const float4*)&cpar[4 * cq];
        #pragma unroll
        for (int i = 0; i < 4; ++i) {
            int e = 4 * eg + i;
            m2s[e * 33 + 4 * cq + 0] = silu(acc[i].x + bb.x);
            m2s[e * 33 + 4 * cq + 1] = silu(acc[i].y + bb.y);
            m2s[e * 33 + 4 * cq + 2] = silu(acc[i].z + bb.z);
            m2s[e * 33 + 4 * cq + 3] = silu(acc[i].w + bb.w);
        }
    }
    __syncthreads();
    if (tid < EPB) {
        float s = 0.f, ss = 0.f;
        #pragma unroll
        for (int c = 0; c < 32; ++c) {
            float v = m2s[tid * 33 + c];
            s += v; ss += v * v;
        }
        float mean = s * 0.03125f;
        float var = ss * 0.03125f - mean * mean;
        float rstd = 1.0f / sqrtf(var + EPS);
        int d = dsi[tid];
        float* Sp = S + (size_t)d * 32;
        #pragma unroll
        for (int c = 0; c < 32; ++c) {
            float v = (m2s[tid * 33 + c] - mean) * rstd * cpar[32 + c] + cpar[64 + c];
            atomicAdd(&Sp[c], v);
        }
        atomicAdd(&cnt[d], 1.0f);
    }
}

// ---------------- node prep: H0 = [LN(feats) | LN(S/cnt)] ----------------
__global__ __launch_bounds__(128) void k_prep(const float* __restrict__ featsk,
                                              const float* __restrict__ S,
                                              const float* __restrict__ cnt,
                                              const float* __restrict__ nn1g,
                                              const float* __restrict__ nn1b,
                                              const float* __restrict__ eng,
                                              const float* __restrict__ enb,
                                              float* __restrict__ H0) {
    int n = blockIdx.x, tid = threadIdx.x;
    __shared__ float red[4];
    float x = featsk[(size_t)n * 768 + tid];
    float s = wave_sum64(x), ss = wave_sum64(x * x);
    if ((tid & 63) == 0) { red[(tid >> 6) * 2] = s; red[(tid >> 6) * 2 + 1] = ss; }
    __syncthreads();
    float S1 = red[0] + red[2], S2 = red[1] + red[3];
    float mean = S1 * (1.0f / 128.0f);
    float var = S2 * (1.0f / 128.0f) - mean * mean;
    float rstd = 1.0f / sqrtf(var + EPS);
    H0[(size_t)n * 160 + tid] = (x - mean) * rstd * nn1g[tid] + nn1b[tid];
    if (tid < 32) {
        float inv = 1.0f / fmaxf(cnt[n], 1.0f);
        float v = S[(size_t)n * 32 + tid] * inv;
        float s2 = v, q2 = v * v;
        #pragma unroll
        for (int off = 16; off > 0; off >>= 1) {
            s2 += __shfl_xor(s2, off, 64);
            q2 += __shfl_xor(q2, off, 64);
        }
        float m2 = s2 * (1.0f / 32.0f);
        float va = q2 * (1.0f / 32.0f) - m2 * m2;
        float rs = 1.0f / sqrtf(va + EPS);
        H0[(size_t)n * 160 + 128 + tid] = (v - m2) * rs * eng[tid] + enb[tid];
    }
}

// ---------------- LN + residual ----------------
__global__ __launch_bounds__(128) void k_ln_res(const float* __restrict__ H2,
                                                float* __restrict__ feats_all, int k,
                                                const float* __restrict__ g,
                                                const float* __restrict__ b) {
    int n = blockIdx.x, tid = threadIdx.x;
    __shared__ float red[4];
    float x = H2[(size_t)n * 128 + tid];
    float s = wave_sum64(x), ss = wave_sum64(x * x);
    if ((tid & 63) == 0) { red[(tid >> 6) * 2] = s; red[(tid >> 6) * 2 + 1] = ss; }
    __syncthreads();
    float S1 = red[0] + red[2], S2 = red[1] + red[3];
    float mean = S1 * (1.0f / 128.0f);
    float var = S2 * (1.0f / 128.0f) - mean * mean;
    float rstd = 1.0f / sqrtf(var + EPS);
    float v = (x - mean) * rstd * g[tid] + b[tid];
    float f = feats_all[(size_t)n * 768 + k * 128 + tid];
    feats_all[(size_t)n * 768 + (k + 1) * 128 + tid] = f + v;
}

// ---------------- graph pooling (batch sorted -> run-length accum) ----------------
__global__ __launch_bounds__(256) void k_pool(const float* __restrict__ F,
                                              const int* __restrict__ batch,
                                              float* __restrict__ G,
                                              float* __restrict__ cntg) {
    __shared__ int bL[32];
    int b0 = blockIdx.x * 32;
    int tid = threadIdx.x;
    int nmax = min(32, N_NODES - b0);
    if (nmax <= 0) return;
    if (tid < nmax) bL[tid] = batch[b0 + tid];
    __syncthreads();
    float accv = 0.f;
    int cur = -1;
    for (int i = 0; i < nmax; ++i) {
        int g = bL[i];
        if (g != cur) {
            if (cur >= 0) atomicAdd(&G[(size_t)cur * 256 + tid], accv);
            cur = g; accv = 0.f;
        }
        accv += F[(size_t)(b0 + i) * 256 + tid];
    }
    if (cur >= 0) atomicAdd(&G[(size_t)cur * 256 + tid], accv);
    if (tid == 0)
        for (int i = 0; i < nmax; ++i) atomicAdd(&cntg[bL[i]], 1.0f);
}

// ---------------- per-graph MLP head ----------------
__global__ __launch_bounds__(256) void k_graph(const float* __restrict__ G,
                                               const float* __restrict__ cntg,
                                               const float* __restrict__ g1W,
                                               const float* __restrict__ g1b,
                                               const float* __restrict__ g2W,
                                               const float* __restrict__ g2b,
                                               const float* __restrict__ g3W,
                                               const float* __restrict__ g3b,
                                               float* __restrict__ out) {
    __shared__ float X[256], Y[256], red[4];
    int g = blockIdx.x, tid = threadIdx.x;
    float inv = 1.0f / fmaxf(cntg[g], 1.0f);
    X[tid] = G[(size_t)g * 256 + tid] * inv;
    __syncthreads();
    float a = g1b[tid];
    for (int j = 0; j < 256; ++j) a = fmaf(X[j], g1W[(size_t)j * 256 + tid], a);
    Y[tid] = silu(a);
    __syncthreads();
    a = g2b[tid];
    for (int j = 0; j < 256; ++j) a = fmaf(Y[j], g2W[(size_t)j * 256 + tid], a);
    float z = silu(a);
    float p = z * g3W[tid];
    p = wave_sum64(p);
    if ((tid & 63) == 0) red[tid >> 6] = p;
    __syncthreads();
    if (tid == 0) out[g] = red[0] + red[1] + red[2] + red[3] + g3b[0];
}

extern "C" void kernel_launch(void* const* d_in, const int* in_sizes, int n_in,
                              void* d_out, int out_size, void* d_ws, size_t ws_size,
                              hipStream_t stream) {
    const int*   atomids = (const int*)d_in[0];
    const float* coords  = (const float*)d_in[1];
    const int*   eidx    = (const int*)d_in[2];
    const int*   batch   = (const int*)d_in[3];
    const float* emb_w   = (const float*)d_in[4];
    const float* eW1     = (const float*)d_in[5];
    const float* eb1     = (const float*)d_in[6];
    const float* eW2     = (const float*)d_in[7];
    const float* eb2     = (const float*)d_in[8];
    const float* en_g    = (const float*)d_in[9];
    const float* en_b    = (const float*)d_in[10];
    const float* nn1_g   = (const float*)d_in[11];
    const float* nn1_b   = (const float*)d_in[12];
    const float* nW1     = (const float*)d_in[13];
    const float* nb1     = (const float*)d_in[14];
    const float* nW2     = (const float*)d_in[15];
    const float* nb2     = (const float*)d_in[16];
    const float* nn2_g   = (const float*)d_in[17];
    const float* nn2_b   = (const float*)d_in[18];
    const float* f1W     = (const float*)d_in[19];
    const float* f1b     = (const float*)d_in[20];
    const float* f2W     = (const float*)d_in[21];
    const float* f2b     = (const float*)d_in[22];
    const float* f3W     = (const float*)d_in[23];
    const float* f3b     = (const float*)d_in[24];
    const float* g1W     = (const float*)d_in[25];
    const float* g1b     = (const float*)d_in[26];
    const float* g2W     = (const float*)d_in[27];
    const float* g2b     = (const float*)d_in[28];
    const float* g3W     = (const float*)d_in[29];
    const float* g3b     = (const float*)d_in[30];
    float* out = (float*)d_out;

    float* ws = (float*)d_ws;
    // fixed layout (floats); all offsets multiples of 4 -> 16B-aligned
    float* feats_all = ws;                       // [10000][768]
    float* feP  = ws + 7680000;                  // [160000][65]
    float* Pab  = ws + 18080000;                 // [10000][1288] (Pa | pad2 | Pb | pad2)
    float* S    = ws + 30960000;                 // [10000][32]
    float* cnt  = ws + 31280000;                 // [10000]
    float* H0   = ws + 31290000;                 // [10000][160]
    float* H2   = ws + 32890000;                 // [10000][128]
    float* H1   = ws + 34170000;                 // [10000][256]
    float* G    = ws + 36730000;                 // [64][256]
    float* cntg = ws + 36746384;                 // [64]
    float* Qseg = ws + 36746448;                 // [seg][648], sized from ws_size
    float* F2   = H0;                            // final phase reuses H0+H2 (2.88M >= 2.56M)
    float* F3   = Pab;                           // final phase reuses Pab

    // dynamic Q segment size (multiple of 128 edges)
    size_t totalf = ws_size / 4;
    long availf = (long)totalf - 36746448L - 256L;
    long segl = (availf > 0) ? (availf / 648) : 0;
    segl = (segl / 128) * 128;
    if (segl > 160000) segl = 160000;
    if (segl < 128) segl = 128;   // minimal fallback
    const int seg = (int)segl;

    k_embed<<<N_NODES, 128, 0, stream>>>(atomids, emb_w, feats_all);
    k_fe<<<N_EDGES / 64, 64, 0, stream>>>(coords, eidx, feP);

    for (int k = 0; k < NK; ++k) {
        const float* eW1k = eW1 + (size_t)k * 321 * 642;
        const float* eb1k = eb1 + (size_t)k * 642;
        const float* eW2k = eW2 + (size_t)k * 642 * 32;
        const float* eb2k = eb2 + (size_t)k * 32;
        const float* engk = en_g + (size_t)k * 32;
        const float* enbk = en_b + (size_t)k * 32;
        const float* nn1gk = nn1_g + (size_t)k * 128;
        const float* nn1bk = nn1_b + (size_t)k * 128;
        const float* nW1k = nW1 + (size_t)k * 160 * 256;
        const float* nb1k = nb1 + (size_t)k * 256;
        const float* nW2k = nW2 + (size_t)k * 256 * 128;
        const float* nb2k = nb2 + (size_t)k * 128;
        const float* nn2gk = nn2_g + (size_t)k * 128;
        const float* nn2bk = nn2_b + (size_t)k * 128;

        // node projections: Pa = feats @ W1[0:128], Pb = feats @ W1[128:256]
        k_gemm<<<dim3(79, 6), 256, 0, stream>>>(feats_all + k * 128, 768, eW1k, 642,
                                                nullptr, Pab, 1288, N_NODES, 642, 128, 0, 0);
        k_gemm<<<dim3(79, 6), 256, 0, stream>>>(feats_all + k * 128, 768, eW1k + 128 * 642, 642,
                                                nullptr, Pab + 644, 1288, N_NODES, 642, 128, 0, 0);
        hipMemsetAsync(S, 0, (size_t)330000 * sizeof(float), stream);

        for (int e0 = 0; e0 < N_EDGES; e0 += seg) {
            int se = min(seg, N_EDGES - e0);     // multiple of 128
            // Q = fe @ W1[256:321] + b1
            k_gemm<<<dim3(se / 128, 6), 256, 0, stream>>>(feP + (size_t)e0 * 65, 65,
                                                          eW1k + 256 * 642, 642, eb1k,
                                                          Qseg, 648, se, 642, 65, 0, 0);
            k_edge<<<se / 128, 256, 0, stream>>>(Qseg, 648, Pab, eidx, e0,
                                                 eW2k, eb2k, engk, enbk, S, cnt);
        }

        k_prep<<<N_NODES, 128, 0, stream>>>(feats_all + k * 128, S, cnt,
                                            nn1gk, nn1bk, engk, enbk, H0);
        k_gemm<<<dim3(79, 2), 256, 0, stream>>>(H0, 160, nW1k, 256, nb1k, H1, 256,
                                                N_NODES, 256, 160, 0, 1);
        k_gemm<<<dim3(79, 1), 256, 0, stream>>>(H1, 256, nW2k, 128, nb2k, H2, 128,
                                                N_NODES, 128, 256, 0, 0);
        k_ln_res<<<N_NODES, 128, 0, stream>>>(H2, feats_all, k, nn2gk, nn2bk);
    }

    // final node MLP
    k_gemm<<<dim3(79, 2), 256, 0, stream>>>(feats_all, 768, f1W, 256, f1b, H1, 256,
                                            N_NODES, 256, 768, 1, 1);
    k_gemm<<<dim3(79, 2), 256, 0, stream>>>(H1, 256, f2W, 256, f2b, F2, 256,
                                            N_NODES, 256, 256, 0, 1);
    k_gemm<<<dim3(79, 2), 256, 0, stream>>>(F2, 256, f3W, 256, f3b, F3, 256,
                                            N_NODES, 256, 256, 0, 1);

    hipMemsetAsync(G, 0, (size_t)(16384 + 64) * sizeof(float), stream);
    k_pool<<<313, 256, 0, stream>>>(F3, batch, G, cntg);
    k_graph<<<N_GRAPHS, 256, 0, stream>>>(G, cntg, g1W, g1b, g2W, g2b, g3W, g3b, out);
}

// Round 3
// 4582.585 us; speedup vs baseline: 2.4121x; 1.6399x over previous
//
#include <hip/hip_runtime.h>
#include <hip/hip_bf16.h>

#define N_NODES 10000
#define N_EDGES 160000
#define N_GRAPHS 64
#define NK 5
#define EPS 1e-5f
#define EPB 128
#define JP 672           // padded edge-MLP width (642 -> 672, pads are true zeros)
#define PSTRIDE 1344     // Pab row stride: [Pa 672 | Pb 672]

__device__ __forceinline__ float silu(float x) { return x / (1.0f + __expf(-x)); }
__device__ __forceinline__ float4 f4fma(float s, float4 w, float4 a) {
    a.x = fmaf(s, w.x, a.x); a.y = fmaf(s, w.y, a.y);
    a.z = fmaf(s, w.z, a.z); a.w = fmaf(s, w.w, a.w);
    return a;
}
__device__ __forceinline__ float wave_sum64(float v) {
    #pragma unroll
    for (int off = 32; off > 0; off >>= 1) v += __shfl_xor(v, off, 64);
    return v;
}

// ---------------- embedding ----------------
__global__ __launch_bounds__(128) void k_embed(const int* __restrict__ atomids,
                                               const float* __restrict__ emb_w,
                                               float* __restrict__ feats_all) {
    int n = blockIdx.x, tid = threadIdx.x;
    feats_all[(size_t)n * 768 + tid] = emb_w[(size_t)atomids[n] * 128 + tid];
}

// ---------------- fourier table, transposed: feT[k][e] ----------------
__global__ __launch_bounds__(64) void k_fe(const float* __restrict__ coords,
                                           const int* __restrict__ eidx,
                                           float* __restrict__ feT) {
    int e = blockIdx.x * 64 + threadIdx.x;
    if (e >= N_EDGES) return;
    int s = eidx[e], d = eidx[N_EDGES + e];
    float dx = coords[s * 3 + 0] - coords[d * 3 + 0];
    float dy = coords[s * 3 + 1] - coords[d * 3 + 1];
    float dz = coords[s * 3 + 2] - coords[d * 3 + 2];
    float d2 = dx * dx + dy * dy + dz * dz;
    float sc = 1.0f;
    #pragma unroll
    for (int i = 0; i < 32; ++i) {
        float x = d2 * sc;
        feT[(size_t)i * N_EDGES + e] = sinf(x);
        feT[(size_t)(32 + i) * N_EDGES + e] = cosf(x);
        sc *= 0.5f;
    }
    feT[(size_t)64 * N_EDGES + e] = d2;
}

// ---------------- W1ab prestage: [128][1344] = [W1a | 0 | W1b | 0] ----------------
__global__ __launch_bounds__(256) void k_w1ab(const float* __restrict__ W1,  // [321][642], rows 0..255 used
                                              float* __restrict__ W1ab) {
    int idx = blockIdx.x * 256 + threadIdx.x;
    if (idx >= 128 * 1344) return;
    int r = idx / 1344, j = idx - r * 1344;
    float v = 0.f;
    if (j < 642) v = W1[(size_t)r * 642 + j];
    else if (j >= 672 && j < 1314) v = W1[(size_t)(128 + r) * 642 + (j - 672)];
    W1ab[idx] = v;
}

// ---------------- fp32 GEMM: C = act(actA(A)[M][K] @ B[K][N] + bias) ----------------
// 128x128 tile, 256 threads, 8x8 micro (cols split as 4+4, 64 apart: 2-way LDS max).
// Requires: K%32==0, lda%4==0, ldb%4==0, N%4==0, A/B/C 16B-aligned.
__global__ __launch_bounds__(256) void k_gemm(const float* __restrict__ A, int lda,
                                              const float* __restrict__ B, int ldb,
                                              const float* __restrict__ bias,
                                              float* __restrict__ C, int ldc,
                                              int M, int N, int K, int siluA, int siluOut) {
    __shared__ float As[32 * 132];   // As[k][m]
    __shared__ float Bs[32 * 132];   // Bs[k][n]
    const int tid = threadIdx.x;
    const int m0 = blockIdx.x * 128, n0 = blockIdx.y * 128;
    const int tm = tid >> 4, tn = tid & 15;  // rows 8*tm.., cols 4*tn and 64+4*tn

    float4 acc[8][2];
    #pragma unroll
    for (int r = 0; r < 8; ++r) { acc[r][0] = make_float4(0,0,0,0); acc[r][1] = make_float4(0,0,0,0); }

    for (int kc = 0; kc < K; kc += 32) {
        #pragma unroll
        for (int i = 0; i < 4; ++i) {            // A: 128 rows x 32 k, float4, transpose into As
            int idx = tid + i * 256;
            int m = idx >> 3, kq = idx & 7;
            int gm = m0 + m;
            int cm = (gm < M) ? gm : (M - 1);
            float4 a = *(const float4*)(A + (size_t)cm * lda + kc + 4 * kq);
            if (gm >= M) a = make_float4(0,0,0,0);
            if (siluA) { a.x = silu(a.x); a.y = silu(a.y); a.z = silu(a.z); a.w = silu(a.w); }
            As[(4 * kq + 0) * 132 + m] = a.x;
            As[(4 * kq + 1) * 132 + m] = a.y;
            As[(4 * kq + 2) * 132 + m] = a.z;
            As[(4 * kq + 3) * 132 + m] = a.w;
        }
        #pragma unroll
        for (int i = 0; i < 4; ++i) {            // B: 32 k x 128 n, float4
            int idx = tid + i * 256;
            int r = idx >> 5, cq = idx & 31;
            int gn = n0 + 4 * cq;
            float4 b = make_float4(0,0,0,0);
            if (gn < N) b = *(const float4*)(B + (size_t)(kc + r) * ldb + gn);
            *(float4*)&Bs[r * 132 + 4 * cq] = b;
        }
        __syncthreads();
        #pragma unroll 4
        for (int kk = 0; kk < 32; ++kk) {
            float4 a0 = *(const float4*)&As[kk * 132 + 8 * tm];
            float4 a1 = *(const float4*)&As[kk * 132 + 8 * tm + 4];
            float4 b0 = *(const float4*)&Bs[kk * 132 + 4 * tn];
            float4 b1 = *(const float4*)&Bs[kk * 132 + 64 + 4 * tn];
            acc[0][0] = f4fma(a0.x, b0, acc[0][0]); acc[0][1] = f4fma(a0.x, b1, acc[0][1]);
            acc[1][0] = f4fma(a0.y, b0, acc[1][0]); acc[1][1] = f4fma(a0.y, b1, acc[1][1]);
            acc[2][0] = f4fma(a0.z, b0, acc[2][0]); acc[2][1] = f4fma(a0.z, b1, acc[2][1]);
            acc[3][0] = f4fma(a0.w, b0, acc[3][0]); acc[3][1] = f4fma(a0.w, b1, acc[3][1]);
            acc[4][0] = f4fma(a1.x, b0, acc[4][0]); acc[4][1] = f4fma(a1.x, b1, acc[4][1]);
            acc[5][0] = f4fma(a1.y, b0, acc[5][0]); acc[5][1] = f4fma(a1.y, b1, acc[5][1]);
            acc[6][0] = f4fma(a1.z, b0, acc[6][0]); acc[6][1] = f4fma(a1.z, b1, acc[6][1]);
            acc[7][0] = f4fma(a1.w, b0, acc[7][0]); acc[7][1] = f4fma(a1.w, b1, acc[7][1]);
        }
        __syncthreads();
    }

    const int gnl = n0 + 4 * tn, gnh = n0 + 64 + 4 * tn;
    #pragma unroll
    for (int r = 0; r < 8; ++r) {
        int gm = m0 + 8 * tm + r;
        if (gm >= M) continue;
        float4 v0 = acc[r][0], v1 = acc[r][1];
        if (gnl < N) {
            if (bias) { v0.x += bias[gnl+0]; v0.y += bias[gnl+1]; v0.z += bias[gnl+2]; v0.w += bias[gnl+3]; }
            if (siluOut) { v0.x = silu(v0.x); v0.y = silu(v0.y); v0.z = silu(v0.z); v0.w = silu(v0.w); }
            *(float4*)&C[(size_t)gm * ldc + gnl] = v0;
        }
        if (gnh < N) {
            if (bias) { v1.x += bias[gnh+0]; v1.y += bias[gnh+1]; v1.z += bias[gnh+2]; v1.w += bias[gnh+3]; }
            if (siluOut) { v1.x = silu(v1.x); v1.y = silu(v1.y); v1.z = silu(v1.z); v1.w = silu(v1.w); }
            *(float4*)&C[(size_t)gm * ldc + gnh] = v1;
        }
    }
}

// ---------------- fused edge kernel (Q GEMM fused in) ----------------
// 128 edges/block. Per 32-col chunk: q = fe@W1chunk (LDS), z = silu(q + Pa[dst] + Pb[src] + b1)
// -> transposed LDS, m2 += z @ W2chunk. Epilogue: +b2, silu, LN, atomic segment-add.
__global__ __launch_bounds__(256) void k_edge(const float* __restrict__ feT,   // [65][N_EDGES]
                                              const float* __restrict__ Pab,   // [N_NODES][1344]
                                              const int* __restrict__ eidx,
                                              const float* __restrict__ W1c,   // [65][642]
                                              const float* __restrict__ b1,    // [642]
                                              const float* __restrict__ W2,    // [642][32]
                                              const float* __restrict__ b2,
                                              const float* __restrict__ eng,
                                              const float* __restrict__ enb,
                                              float* __restrict__ S,
                                              float* __restrict__ cnt) {
    __shared__ float feTs[65 * 132];   // [k][e]
    __shared__ float W1s[65 * 36];     // [k][j]
    __shared__ float Zs[32 * 132];     // [j][e]; reused as m2s[128][33]
    __shared__ float W2s[32 * 36];     // [j][c]
    __shared__ float b1s[JP];
    __shared__ int dsi[EPB], ssi[EPB];
    __shared__ float cpar[96];         // b2 | eng | enb

    const int tid = threadIdx.x;
    const int eb = blockIdx.x * EPB;

    if (tid < EPB) {
        ssi[tid] = eidx[eb + tid];
        dsi[tid] = eidx[N_EDGES + eb + tid];
    }
    for (int j = tid; j < JP; j += 256) b1s[j] = (j < 642) ? b1[j] : 0.f;
    if (tid < 32) cpar[tid] = b2[tid];
    else if (tid < 64) cpar[tid] = eng[tid - 32];
    else if (tid < 96) cpar[tid] = enb[tid - 64];
    for (int idx = tid; idx < 65 * 32; idx += 256) {
        int k = idx >> 5, q = idx & 31;
        *(float4*)&feTs[k * 132 + 4 * q] = *(const float4*)(feT + (size_t)k * N_EDGES + eb + 4 * q);
    }
    __syncthreads();

    const int cq = tid & 7, eg = tid >> 3;   // edges 4*eg.., cols 4*cq.. (within chunk)
    float4 accm[4];
    #pragma unroll
    for (int i = 0; i < 4; ++i) accm[i] = make_float4(0,0,0,0);

    for (int jc = 0; jc < JP; jc += 32) {
        // prefetch gathers early (hidden behind the 65-deep k-loop)
        float4 pa[4], pb[4];
        #pragma unroll
        for (int i = 0; i < 4; ++i) {
            pa[i] = *(const float4*)(Pab + (size_t)dsi[4*eg+i] * PSTRIDE + jc + 4 * cq);
            pb[i] = *(const float4*)(Pab + (size_t)ssi[4*eg+i] * PSTRIDE + JP + jc + 4 * cq);
        }
        // stage W1 chunk (rows of 642 are unaligned for float4 -> scalar)
        for (int idx = tid; idx < 65 * 32; idx += 256) {
            int k = idx >> 5, j = idx & 31;
            int gj = jc + j;
            W1s[k * 36 + j] = (gj < 642) ? W1c[(size_t)k * 642 + gj] : 0.f;
        }
        // stage W2 chunk [32][32]
        {
            int r = tid >> 3, c4 = tid & 7;
            int gr = jc + r;
            float4 w = make_float4(0,0,0,0);
            if (gr < 642) w = *(const float4*)(W2 + (size_t)gr * 32 + 4 * c4);
            *(float4*)&W2s[r * 36 + 4 * c4] = w;
        }
        __syncthreads();

        // q = fe @ W1 chunk
        float4 aq[4];
        #pragma unroll
        for (int i = 0; i < 4; ++i) aq[i] = make_float4(0,0,0,0);
        #pragma unroll 5
        for (int k = 0; k < 65; ++k) {
            float4 f = *(const float4*)&feTs[k * 132 + 4 * eg];
            float4 w = *(const float4*)&W1s[k * 36 + 4 * cq];
            aq[0] = f4fma(f.x, w, aq[0]);
            aq[1] = f4fma(f.y, w, aq[1]);
            aq[2] = f4fma(f.z, w, aq[2]);
            aq[3] = f4fma(f.w, w, aq[3]);
        }
        // z = silu(q + pa + pb + b1) -> Zs[j][e]   (pads: all terms zero, silu(0)=0)
        float4 bb = *(const float4*)&b1s[jc + 4 * cq];
        #pragma unroll
        for (int i = 0; i < 4; ++i) {
            int e = 4 * eg + i;
            Zs[(4*cq+0) * 132 + e] = silu(aq[i].x + pa[i].x + pb[i].x + bb.x);
            Zs[(4*cq+1) * 132 + e] = silu(aq[i].y + pa[i].y + pb[i].y + bb.y);
            Zs[(4*cq+2) * 132 + e] = silu(aq[i].z + pa[i].z + pb[i].z + bb.z);
            Zs[(4*cq+3) * 132 + e] = silu(aq[i].w + pa[i].w + pb[i].w + bb.w);
        }
        __syncthreads();
        #pragma unroll 4
        for (int kk = 0; kk < 32; ++kk) {
            float4 zr = *(const float4*)&Zs[kk * 132 + 4 * eg];
            float4 w  = *(const float4*)&W2s[kk * 36 + 4 * cq];
            accm[0] = f4fma(zr.x, w, accm[0]);
            accm[1] = f4fma(zr.y, w, accm[1]);
            accm[2] = f4fma(zr.z, w, accm[2]);
            accm[3] = f4fma(zr.w, w, accm[3]);
        }
        __syncthreads();
    }

    // m2 = silu(accm + b2) -> m2s (reuse Zs)
    float* m2s = Zs;
    {
        float4 bb2 = *(const float4*)&cpar[4 * cq];
        #pragma unroll
        for (int i = 0; i < 4; ++i) {
            int e = 4 * eg + i;
            m2s[e * 33 + 4*cq + 0] = silu(accm[i].x + bb2.x);
            m2s[e * 33 + 4*cq + 1] = silu(accm[i].y + bb2.y);
            m2s[e * 33 + 4*cq + 2] = silu(accm[i].z + bb2.z);
            m2s[e * 33 + 4*cq + 3] = silu(accm[i].w + bb2.w);
        }
    }
    __syncthreads();
    if (tid < EPB) {
        float s = 0.f, ss = 0.f;
        #pragma unroll
        for (int c = 0; c < 32; ++c) {
            float v = m2s[tid * 33 + c];
            s += v; ss += v * v;
        }
        float mean = s * 0.03125f;
        float var = ss * 0.03125f - mean * mean;
        float rstd = 1.0f / sqrtf(var + EPS);
        int d = dsi[tid];
        float* Sp = S + (size_t)d * 32;
        #pragma unroll
        for (int c = 0; c < 32; ++c) {
            float v = (m2s[tid * 33 + c] - mean) * rstd * cpar[32 + c] + cpar[64 + c];
            atomicAdd(&Sp[c], v);
        }
        atomicAdd(&cnt[d], 1.0f);
    }
}

// ---------------- node prep: H0 = [LN(feats) | LN(S/cnt)] ----------------
__global__ __launch_bounds__(128) void k_prep(const float* __restrict__ featsk,
                                              const float* __restrict__ S,
                                              const float* __restrict__ cnt,
                                              const float* __restrict__ nn1g,
                                              const float* __restrict__ nn1b,
                                              const float* __restrict__ eng,
                                              const float* __restrict__ enb,
                                              float* __restrict__ H0) {
    int n = blockIdx.x, tid = threadIdx.x;
    __shared__ float red[4];
    float x = featsk[(size_t)n * 768 + tid];
    float s = wave_sum64(x), ss = wave_sum64(x * x);
    if ((tid & 63) == 0) { red[(tid >> 6) * 2] = s; red[(tid >> 6) * 2 + 1] = ss; }
    __syncthreads();
    float S1 = red[0] + red[2], S2 = red[1] + red[3];
    float mean = S1 * (1.0f / 128.0f);
    float var = S2 * (1.0f / 128.0f) - mean * mean;
    float rstd = 1.0f / sqrtf(var + EPS);
    H0[(size_t)n * 160 + tid] = (x - mean) * rstd * nn1g[tid] + nn1b[tid];
    if (tid < 32) {
        float inv = 1.0f / fmaxf(cnt[n], 1.0f);
        float v = S[(size_t)n * 32 + tid] * inv;
        float s2 = v, q2 = v * v;
        #pragma unroll
        for (int off = 16; off > 0; off >>= 1) {
            s2 += __shfl_xor(s2, off, 64);
            q2 += __shfl_xor(q2, off, 64);
        }
        float m2 = s2 * (1.0f / 32.0f);
        float va = q2 * (1.0f / 32.0f) - m2 * m2;
        float rs = 1.0f / sqrtf(va + EPS);
        H0[(size_t)n * 160 + 128 + tid] = (v - m2) * rs * eng[tid] + enb[tid];
    }
}

// ---------------- LN + residual ----------------
__global__ __launch_bounds__(128) void k_ln_res(const float* __restrict__ H2,
                                                float* __restrict__ feats_all, int k,
                                                const float* __restrict__ g,
                                                const float* __restrict__ b) {
    int n = blockIdx.x, tid = threadIdx.x;
    __shared__ float red[4];
    float x = H2[(size_t)n * 128 + tid];
    float s = wave_sum64(x), ss = wave_sum64(x * x);
    if ((tid & 63) == 0) { red[(tid >> 6) * 2] = s; red[(tid >> 6) * 2 + 1] = ss; }
    __syncthreads();
    float S1 = red[0] + red[2], S2 = red[1] + red[3];
    float mean = S1 * (1.0f / 128.0f);
    float var = S2 * (1.0f / 128.0f) - mean * mean;
    float rstd = 1.0f / sqrtf(var + EPS);
    float v = (x - mean) * rstd * g[tid] + b[tid];
    float f = feats_all[(size_t)n * 768 + k * 128 + tid];
    feats_all[(size_t)n * 768 + (k + 1) * 128 + tid] = f + v;
}

// ---------------- graph pooling (batch sorted -> run-length accum) ----------------
__global__ __launch_bounds__(256) void k_pool(const float* __restrict__ F,
                                              const int* __restrict__ batch,
                                              float* __restrict__ G,
                                              float* __restrict__ cntg) {
    __shared__ int bL[32];
    int b0 = blockIdx.x * 32;
    int tid = threadIdx.x;
    int nmax = min(32, N_NODES - b0);
    if (nmax <= 0) return;
    if (tid < nmax) bL[tid] = batch[b0 + tid];
    __syncthreads();
    float accv = 0.f;
    int cur = -1;
    for (int i = 0; i < nmax; ++i) {
        int g = bL[i];
        if (g != cur) {
            if (cur >= 0) atomicAdd(&G[(size_t)cur * 256 + tid], accv);
            cur = g; accv = 0.f;
        }
        accv += F[(size_t)(b0 + i) * 256 + tid];
    }
    if (cur >= 0) atomicAdd(&G[(size_t)cur * 256 + tid], accv);
    if (tid == 0)
        for (int i = 0; i < nmax; ++i) atomicAdd(&cntg[bL[i]], 1.0f);
}

// ---------------- per-graph MLP head ----------------
__global__ __launch_bounds__(256) void k_graph(const float* __restrict__ G,
                                               const float* __restrict__ cntg,
                                               const float* __restrict__ g1W,
                                               const float* __restrict__ g1b,
                                               const float* __restrict__ g2W,
                                               const float* __restrict__ g2b,
                                               const float* __restrict__ g3W,
                                               const float* __restrict__ g3b,
                                               float* __restrict__ out) {
    __shared__ float X[256], Y[256], red[4];
    int g = blockIdx.x, tid = threadIdx.x;
    float inv = 1.0f / fmaxf(cntg[g], 1.0f);
    X[tid] = G[(size_t)g * 256 + tid] * inv;
    __syncthreads();
    float a = g1b[tid];
    for (int j = 0; j < 256; ++j) a = fmaf(X[j], g1W[(size_t)j * 256 + tid], a);
    Y[tid] = silu(a);
    __syncthreads();
    a = g2b[tid];
    for (int j = 0; j < 256; ++j) a = fmaf(Y[j], g2W[(size_t)j * 256 + tid], a);
    float z = silu(a);
    float p = z * g3W[tid];
    p = wave_sum64(p);
    if ((tid & 63) == 0) red[tid >> 6] = p;
    __syncthreads();
    if (tid == 0) out[g] = red[0] + red[1] + red[2] + red[3] + g3b[0];
}

extern "C" void kernel_launch(void* const* d_in, const int* in_sizes, int n_in,
                              void* d_out, int out_size, void* d_ws, size_t ws_size,
                              hipStream_t stream) {
    const int*   atomids = (const int*)d_in[0];
    const float* coords  = (const float*)d_in[1];
    const int*   eidx    = (const int*)d_in[2];
    const int*   batch   = (const int*)d_in[3];
    const float* emb_w   = (const float*)d_in[4];
    const float* eW1     = (const float*)d_in[5];
    const float* eb1     = (const float*)d_in[6];
    const float* eW2     = (const float*)d_in[7];
    const float* eb2     = (const float*)d_in[8];
    const float* en_g    = (const float*)d_in[9];
    const float* en_b    = (const float*)d_in[10];
    const float* nn1_g   = (const float*)d_in[11];
    const float* nn1_b   = (const float*)d_in[12];
    const float* nW1     = (const float*)d_in[13];
    const float* nb1     = (const float*)d_in[14];
    const float* nW2     = (const float*)d_in[15];
    const float* nb2     = (const float*)d_in[16];
    const float* nn2_g   = (const float*)d_in[17];
    const float* nn2_b   = (const float*)d_in[18];
    const float* f1W     = (const float*)d_in[19];
    const float* f1b     = (const float*)d_in[20];
    const float* f2W     = (const float*)d_in[21];
    const float* f2b     = (const float*)d_in[22];
    const float* f3W     = (const float*)d_in[23];
    const float* f3b     = (const float*)d_in[24];
    const float* g1W     = (const float*)d_in[25];
    const float* g1b     = (const float*)d_in[26];
    const float* g2W     = (const float*)d_in[27];
    const float* g2b     = (const float*)d_in[28];
    const float* g3W     = (const float*)d_in[29];
    const float* g3b     = (const float*)d_in[30];
    float* out = (float*)d_out;

    float* ws = (float*)d_ws;
    // layout (float indices, all 16B-aligned); total 32,038,480 floats = 128.2 MB
    float* feats_all = ws;                        // [10000][768]
    float* feT   = ws + 7680000;                  // [65][160000]
    float* Pab   = ws + 18080000;                 // [10000][1344]
    float* S     = ws + 31520000;                 // [10000][32]
    float* cnt   = ws + 31840000;                 // [10000]
    float* W1ab  = ws + 31850000;                 // [128][1344]
    float* G     = ws + 32022032;                 // [64][256]
    float* cntg  = ws + 32038416;                 // [64]
    // node-phase temporaries overlay Pab (dead between edge phase and next layer's GEMM)
    float* H0 = Pab;                              // [10000][160]
    float* H1 = Pab + 1600000;                    // [10000][256]
    float* H2 = Pab + 4160000;                    // [10000][128]
    float* F1 = Pab;                              // [10000][256]
    float* F2 = Pab + 2560000;                    // [10000][256]
    float* F3 = Pab + 5120000;                    // [10000][256]

    k_embed<<<N_NODES, 128, 0, stream>>>(atomids, emb_w, feats_all);
    k_fe<<<N_EDGES / 64, 64, 0, stream>>>(coords, eidx, feT);

    for (int k = 0; k < NK; ++k) {
        const float* eW1k = eW1 + (size_t)k * 321 * 642;
        const float* eb1k = eb1 + (size_t)k * 642;
        const float* eW2k = eW2 + (size_t)k * 642 * 32;
        const float* eb2k = eb2 + (size_t)k * 32;
        const float* engk = en_g + (size_t)k * 32;
        const float* enbk = en_b + (size_t)k * 32;
        const float* nn1gk = nn1_g + (size_t)k * 128;
        const float* nn1bk = nn1_b + (size_t)k * 128;
        const float* nW1k = nW1 + (size_t)k * 160 * 256;
        const float* nb1k = nb1 + (size_t)k * 256;
        const float* nW2k = nW2 + (size_t)k * 256 * 128;
        const float* nb2k = nb2 + (size_t)k * 128;
        const float* nn2gk = nn2_g + (size_t)k * 128;
        const float* nn2bk = nn2_b + (size_t)k * 128;

        // padded fused node-projection weight, then Pab = feats @ W1ab
        k_w1ab<<<672, 256, 0, stream>>>(eW1k, W1ab);
        k_gemm<<<dim3(79, 11), 256, 0, stream>>>(feats_all + k * 128, 768, W1ab, 1344,
                                                 nullptr, Pab, 1344, N_NODES, 1344, 128, 0, 0);
        hipMemsetAsync(S, 0, (size_t)330000 * sizeof(float), stream);
        k_edge<<<N_EDGES / EPB, 256, 0, stream>>>(feT, Pab, eidx, eW1k + 256 * 642, eb1k,
                                                  eW2k, eb2k, engk, enbk, S, cnt);
        k_prep<<<N_NODES, 128, 0, stream>>>(feats_all + k * 128, S, cnt,
                                            nn1gk, nn1bk, engk, enbk, H0);
        k_gemm<<<dim3(79, 2), 256, 0, stream>>>(H0, 160, nW1k, 256, nb1k, H1, 256,
                                                N_NODES, 256, 160, 0, 1);
        k_gemm<<<dim3(79, 1), 256, 0, stream>>>(H1, 256, nW2k, 128, nb2k, H2, 128,
                                                N_NODES, 128, 256, 0, 0);
        k_ln_res<<<N_NODES, 128, 0, stream>>>(H2, feats_all, k, nn2gk, nn2bk);
    }

    // final node MLP (F1/F2/F3 overlay Pab)
    k_gemm<<<dim3(79, 2), 256, 0, stream>>>(feats_all, 768, f1W, 256, f1b, F1, 256,
                                            N_NODES, 256, 768, 1, 1);
    k_gemm<<<dim3(79, 2), 256, 0, stream>>>(F1, 256, f2W, 256, f2b, F2, 256,
                                            N_NODES, 256, 256, 0, 1);
    k_gemm<<<dim3(79, 2), 256, 0, stream>>>(F2, 256, f3W, 256, f3b, F3, 256,
                                            N_NODES, 256, 256, 0, 1);

    hipMemsetAsync(G, 0, (size_t)(16384 + 64) * sizeof(float), stream);
    k_pool<<<313, 256, 0, stream>>>(F3, batch, G, cntg);
    k_graph<<<N_GRAPHS, 256, 0, stream>>>(G, cntg, g1W, g1b, g2W, g2b, g3W, g3b, out);
}